// Round 1
// baseline (2405.001 us; speedup 1.0000x reference)
//
#include <hip/hip_runtime.h>

// DeSELayer: per-sample CP-ALS(rank4, 20 it) -> rank_fc -> SE fc -> sigmoid gate.
// Gram-trick: iterations run on Gram = T0^T T0 (196x196, LDS-resident).
// 1 workgroup (1024 thr) per sample; grid = 256 = #CUs.

#define EPSV 1e-6f

#define SM_G    0
#define SM_COF  16
#define SM_GINV 32
#define SM_M    48
#define SM_ATA  104

struct SMem {
  float gram[196 * 197];          // 154,448 B, stride 197 (odd -> conflict-free)
  union {
    float stage[8 * 200];         // phase-1 staging (8 rows x 200-padded)
    struct {
      float H[196 * 5];           // stride 5
      float Y[196 * 5];           // stride 5; epilogue: y[512] @0, z[32] @512
    } p2;
  } u;
  float B[56];                    // B[j][r] flat j*4+r
  float C[56];
  float Sm[120];                  // G,COF,GINV,M(56),ATA
};

__device__ __forceinline__ float rlane(float v, int l) {
  return __uint_as_float(__builtin_amdgcn_readlane(__float_as_uint(v), l));
}
__device__ __forceinline__ void fence_lds() { __threadfence_block(); }

// (V^T V)[r][s] for lanes (meaningful for l<16); V = 14x4 flat
__device__ __forceinline__ float gram16(const float* V, int l) {
  int r = (l >> 2) & 3, s = l & 3;
  float a = 0.f;
#pragma unroll
  for (int j = 0; j < 14; ++j) a += V[j * 4 + r] * V[j * 4 + s];
  return a;
}

// lanes 0..15 of wave 0: Sm[G..G+15] -> Sm[GINV..] via adjugate (G symmetric SPD + eps)
__device__ __forceinline__ void inv4x4(SMem* sm, int l) {
  if (l < 16) {
    float g[16];
#pragma unroll
    for (int t = 0; t < 16; ++t) g[t] = sm->Sm[SM_G + t];
    int r = l >> 2, s = l & 3;
    int r0 = (r == 0) ? 1 : 0, r1 = (r <= 1) ? 2 : 1, r2 = (r <= 2) ? 3 : 2;
    int c0 = (s == 0) ? 1 : 0, c1 = (s <= 1) ? 2 : 1, c2 = (s <= 2) ? 3 : 2;
    float a00 = g[r0 * 4 + c0], a01 = g[r0 * 4 + c1], a02 = g[r0 * 4 + c2];
    float a10 = g[r1 * 4 + c0], a11 = g[r1 * 4 + c1], a12 = g[r1 * 4 + c2];
    float a20 = g[r2 * 4 + c0], a21 = g[r2 * 4 + c1], a22 = g[r2 * 4 + c2];
    float d3 = a00 * (a11 * a22 - a12 * a21) - a01 * (a10 * a22 - a12 * a20)
             + a02 * (a10 * a21 - a11 * a20);
    sm->Sm[SM_COF + l] = ((r + s) & 1) ? -d3 : d3;
  }
  fence_lds();
  if (l < 16) {
    float det = sm->Sm[SM_G + 0] * sm->Sm[SM_COF + 0] + sm->Sm[SM_G + 1] * sm->Sm[SM_COF + 1]
              + sm->Sm[SM_G + 2] * sm->Sm[SM_COF + 2] + sm->Sm[SM_G + 3] * sm->Sm[SM_COF + 3];
    int r = l >> 2, s = l & 3;
    sm->Sm[SM_GINV + l] = sm->Sm[SM_COF + s * 4 + r] / det;  // adj = cof^T
  }
  fence_lds();
}

// wave 0: H[p][r] = sum_s B[j][s]C[k][s] * Ginv[s][r]; zero Y for next accumulation
__device__ __forceinline__ void computeH_zeroY(SMem* sm, int l) {
#pragma unroll
  for (int k4 = 0; k4 < 4; ++k4) {
    int p = l + 64 * k4;
    if (p < 196) {
      int j = p / 14, kk = p - j * 14;
      float kr[4];
#pragma unroll
      for (int s = 0; s < 4; ++s) kr[s] = sm->B[j * 4 + s] * sm->C[kk * 4 + s];
#pragma unroll
      for (int r = 0; r < 4; ++r) {
        float h = kr[0] * sm->Sm[SM_GINV + 0 + r] + kr[1] * sm->Sm[SM_GINV + 4 + r]
                + kr[2] * sm->Sm[SM_GINV + 8 + r] + kr[3] * sm->Sm[SM_GINV + 12 + r];
        sm->u.p2.H[p * 5 + r] = h;
      }
    }
  }
#pragma unroll
  for (int z = 0; z < 16; ++z) {
    int idx = l + 64 * z;
    if (idx < 980) sm->u.p2.Y[idx] = 0.f;
  }
}

__device__ __forceinline__ void initial_H(SMem* sm, int l) {
  float btb = gram16(sm->B, l);
  float ctc = gram16(sm->C, l);
  if (l < 16) {
    float dg = ((l >> 2) == (l & 3)) ? EPSV : 0.f;
    sm->Sm[SM_G + l] = btb * ctc + dg;
  }
  fence_lds();
  inv4x4(sm, l);
  computeH_zeroY(sm, l);
}

// wave 0: ATA in Sm[ATA], Y current. Updates B, C, then next H; zeroes Y.
__device__ __forceinline__ void factor_update(SMem* sm, int l) {
  int jj = l >> 2, r = l & 3;
  float dg = ((l >> 2) == (l & 3)) ? EPSV : 0.f;
  // --- B update: G_B = ATA o CtC(old) + eps ---
  float ctc_old = gram16(sm->C, l);
  if (l < 16) sm->Sm[SM_G + l] = sm->Sm[SM_ATA + l] * ctc_old + dg;
  fence_lds();
  inv4x4(sm, l);
  if (l < 56) {
    float m = 0.f;
#pragma unroll
    for (int k = 0; k < 14; ++k) m += sm->u.p2.Y[(jj * 14 + k) * 5 + r] * sm->C[k * 4 + r];
    sm->Sm[SM_M + l] = m;
  }
  fence_lds();
  if (l < 56) {
    float bn = 0.f;
#pragma unroll
    for (int s = 0; s < 4; ++s) bn += sm->Sm[SM_M + jj * 4 + s] * sm->Sm[SM_GINV + s * 4 + r];
    sm->B[l] = bn;
  }
  fence_lds();
  // --- C update: G_C = ATA o BtB(new) + eps ---
  float btb = gram16(sm->B, l);
  if (l < 16) sm->Sm[SM_G + l] = sm->Sm[SM_ATA + l] * btb + dg;
  fence_lds();
  inv4x4(sm, l);
  if (l < 56) {
    float m = 0.f;
#pragma unroll
    for (int j = 0; j < 14; ++j) m += sm->u.p2.Y[(j * 14 + jj) * 5 + r] * sm->B[j * 4 + r];
    sm->Sm[SM_M + l] = m;
  }
  fence_lds();
  if (l < 56) {
    float cn = 0.f;
#pragma unroll
    for (int s = 0; s < 4; ++s) cn += sm->Sm[SM_M + jj * 4 + s] * sm->Sm[SM_GINV + s * 4 + r];
    sm->C[l] = cn;
  }
  fence_lds();
  // --- next-iteration H: G_A = BtB(new) o CtC(new) + eps ---
  float ctc_new = gram16(sm->C, l);
  if (l < 16) sm->Sm[SM_G + l] = btb * ctc_new + dg;
  fence_lds();
  inv4x4(sm, l);
  computeH_zeroY(sm, l);
}

extern "C" __global__ void __launch_bounds__(1024)
dese_kernel(const float* __restrict__ x, const float* __restrict__ B0,
            const float* __restrict__ C0, const float* __restrict__ w1,
            const float* __restrict__ w2, const float* __restrict__ fw1,
            const float* __restrict__ fw2, float* __restrict__ out) {
  extern __shared__ char smraw[];
  SMem* sm = (SMem*)smraw;
  const int tid = threadIdx.x;
  const int b = blockIdx.x;
  const int wv = tid >> 6;
  const int lane = tid & 63;
  const float* xb = x + (size_t)b * 100352;

  // load per-sample B0, C0 (A0 is dead: first ALS step overwrites A)
  if (tid < 56) sm->B[tid] = B0[b * 56 + tid];
  if (tid >= 64 && tid < 120) sm->C[tid - 64] = C0[b * 56 + (tid - 64)];

  // ================= Phase 1: Gram = T0^T T0 (196x196, K=512) =================
  {
    float acc[4][4][4];
#pragma unroll
    for (int a = 0; a < 4; ++a)
#pragma unroll
      for (int i = 0; i < 4; ++i)
#pragma unroll
        for (int j = 0; j < 4; ++j) acc[a][i][j] = 0.f;

    const float4* xs4 = (const float4*)xb;
    for (int ch = 0; ch < 64; ++ch) {
      __syncthreads();
      if (tid < 392) {  // stage 8 rows x 196 floats, coalesced float4
        float4 v = xs4[ch * 392 + tid];
        int row = tid / 49, col = tid - row * 49;
        *(float4*)&sm->u.stage[row * 200 + col * 4] = v;
      }
      __syncthreads();
      if (lane < 49) {
#pragma unroll
        for (int ii = 0; ii < 8; ++ii) {
          float4 bv = *(const float4*)&sm->u.stage[ii * 200 + lane * 4];
          float bb[4] = {bv.x, bv.y, bv.z, bv.w};
#pragma unroll
          for (int t3 = 0; t3 < 4; ++t3) {
            int tp = wv + 16 * t3;       // wave-uniform
            if (tp < 49) {
              float4 av = *(const float4*)&sm->u.stage[ii * 200 + tp * 4];
              float aa[4] = {av.x, av.y, av.z, av.w};
#pragma unroll
              for (int ai = 0; ai < 4; ++ai)
#pragma unroll
                for (int bi = 0; bi < 4; ++bi) acc[t3][ai][bi] += aa[ai] * bb[bi];
            }
          }
        }
      }
    }
    __syncthreads();
    if (lane < 49) {
#pragma unroll
      for (int t3 = 0; t3 < 4; ++t3) {
        int tp = wv + 16 * t3;
        if (tp < 49) {
#pragma unroll
          for (int ai = 0; ai < 4; ++ai)
#pragma unroll
            for (int bi = 0; bi < 4; ++bi)
              sm->gram[(tp * 4 + ai) * 197 + lane * 4 + bi] = acc[t3][ai][bi];
        }
      }
    }
  }
  __syncthreads();

  // ================= Phase 2: 19 ALS iteration bodies on Gram =================
  // pre: H_1 from (B0,C0); iter i: Y=Gram*H, ATA=H^T Y, B,C updates, next H.
  // After iter 18 H == H_20; step-20 B/C are dead in the reference.
  if (tid < 64) initial_H(sm, lane);
  __syncthreads();

  for (int it = 0; it < 19; ++it) {
    // ---- Y[p][r] = sum_q Gram[p][q] H[q][r], 4-way q-split + LDS atomics ----
    {
      int qg = tid >> 8;        // 0..3  (wave-uniform: 256-aligned groups)
      int pp = tid & 255;       // p (active < 196)
      float hreg[4];            // window H[qg*49 .. qg*49+48][0..3] dense across lanes
#pragma unroll
      for (int k = 0; k < 4; ++k) {
        int wi = 64 * k + lane;
        int q = qg * 49 + (wi >> 2);
        hreg[k] = (wi < 196) ? sm->u.p2.H[q * 5 + (wi & 3)] : 0.f;
      }
      if (pp < 196) {
        const float* grow = sm->gram + pp * 197 + qg * 49;
        float a0 = 0.f, a1 = 0.f, a2 = 0.f, a3 = 0.f;
#pragma unroll
        for (int qq = 0; qq < 49; ++qq) {
          float g = grow[qq];
          a0 += g * rlane(hreg[(4 * qq + 0) >> 6], (4 * qq + 0) & 63);
          a1 += g * rlane(hreg[(4 * qq + 1) >> 6], (4 * qq + 1) & 63);
          a2 += g * rlane(hreg[(4 * qq + 2) >> 6], (4 * qq + 2) & 63);
          a3 += g * rlane(hreg[(4 * qq + 3) >> 6], (4 * qq + 3) & 63);
        }
        atomicAdd(&sm->u.p2.Y[pp * 5 + 0], a0);
        atomicAdd(&sm->u.p2.Y[pp * 5 + 1], a1);
        atomicAdd(&sm->u.p2.Y[pp * 5 + 2], a2);
        atomicAdd(&sm->u.p2.Y[pp * 5 + 3], a3);
      }
    }
    __syncthreads();
    // ---- ATA[r][s] = sum_p H[p][r] Y[p][s]; wave w handles (r,s)=w ----
    {
      int r = wv >> 2, s = wv & 3;
      float a = 0.f;
#pragma unroll
      for (int k4 = 0; k4 < 4; ++k4) {
        int p = lane + 64 * k4;
        if (p < 196) a += sm->u.p2.H[p * 5 + r] * sm->u.p2.Y[p * 5 + s];
      }
#pragma unroll
      for (int m = 32; m > 0; m >>= 1) a += __shfl_xor(a, m, 64);
      if (lane == 0) sm->Sm[SM_ATA + wv] = a;
    }
    __syncthreads();
    if (tid < 64) factor_update(sm, lane);
    __syncthreads();
  }

  // ================= Epilogue =================
  // y[i] = w2 . relu(w1 . (T0[i,:] H))   for i in 0..511
  {
    float hr[13];  // dense H (4p+r) spread over lanes, all waves load
#pragma unroll
    for (int k = 0; k < 13; ++k) {
      int d = 64 * k + lane;
      hr[k] = (d < 784) ? sm->u.p2.H[(d >> 2) * 5 + (d & 3)] : 0.f;
    }
    if (tid < 512) {
      const float4* row = (const float4*)(xb + tid * 196);
      float a0 = 0.f, a1 = 0.f, a2 = 0.f, a3 = 0.f;
#pragma unroll
      for (int f4 = 0; f4 < 49; ++f4) {
        float4 v = row[f4];
        float vv[4] = {v.x, v.y, v.z, v.w};
#pragma unroll
        for (int j = 0; j < 4; ++j) {
          int d = 16 * f4 + 4 * j;
          a0 += vv[j] * rlane(hr[(d + 0) >> 6], (d + 0) & 63);
          a1 += vv[j] * rlane(hr[(d + 1) >> 6], (d + 1) & 63);
          a2 += vv[j] * rlane(hr[(d + 2) >> 6], (d + 2) & 63);
          a3 += vv[j] * rlane(hr[(d + 3) >> 6], (d + 3) & 63);
        }
      }
      float y = 0.f;
#pragma unroll
      for (int s = 0; s < 4; ++s) {
        float pre = w1[s * 4 + 0] * a0 + w1[s * 4 + 1] * a1 + w1[s * 4 + 2] * a2
                  + w1[s * 4 + 3] * a3;
        y += w2[s] * fmaxf(pre, 0.f);
      }
      sm->u.p2.Y[tid] = y;
    }
  }
  __syncthreads();
  // z[u] = relu(sum_c y[c] fw1[u][c]) : 32 lanes per u, half-wave reduce
  {
    int u = tid >> 5, lc = tid & 31;
    float a = 0.f;
#pragma unroll
    for (int k = 0; k < 16; ++k) {
      int c = lc + 32 * k;
      a += sm->u.p2.Y[c] * fw1[u * 512 + c];
    }
    a += __shfl_xor(a, 1, 64);
    a += __shfl_xor(a, 2, 64);
    a += __shfl_xor(a, 4, 64);
    a += __shfl_xor(a, 8, 64);
    a += __shfl_xor(a, 16, 64);
    if (lc == 0) sm->u.p2.Y[512 + u] = fmaxf(a, 0.f);
  }
  __syncthreads();
  // gate[c] = sigmoid(sum_u z[u] fw2[c][u])
  if (tid < 512) {
    const float4* f2r = (const float4*)(fw2 + tid * 32);
    float za = 0.f;
#pragma unroll
    for (int u4 = 0; u4 < 8; ++u4) {
      float4 fv = f2r[u4];
      za += fv.x * sm->u.p2.Y[512 + u4 * 4 + 0];
      za += fv.y * sm->u.p2.Y[512 + u4 * 4 + 1];
      za += fv.z * sm->u.p2.Y[512 + u4 * 4 + 2];
      za += fv.w * sm->u.p2.Y[512 + u4 * 4 + 3];
    }
    float g = 1.f / (1.f + __expf(-za));
    sm->u.p2.Y[tid] = g;  // y dead -> reuse as gate
  }
  __syncthreads();
  // out = x * gate  (float4, coalesced; 49 float4 per channel)
  {
    const float4* xi = (const float4*)xb;
    float4* oo = (float4*)(out + (size_t)b * 100352);
#pragma unroll
    for (int t = 0; t < 25; ++t) {
      int v = tid + t * 1024;
      if (v < 25088) {
        float4 q = xi[v];
        float g = sm->u.p2.Y[v / 49];
        oo[v] = make_float4(q.x * g, q.y * g, q.z * g, q.w * g);
      }
    }
  }
}

extern "C" void kernel_launch(void* const* d_in, const int* in_sizes, int n_in,
                              void* d_out, int out_size, void* d_ws, size_t ws_size,
                              hipStream_t stream) {
  (void)in_sizes; (void)n_in; (void)d_ws; (void)ws_size; (void)out_size;
  const float* x   = (const float*)d_in[0];
  // d_in[1] = A0: unused (overwritten before first use in the reference)
  const float* B0  = (const float*)d_in[2];
  const float* C0  = (const float*)d_in[3];
  const float* w1  = (const float*)d_in[4];
  const float* w2  = (const float*)d_in[5];
  const float* fw1 = (const float*)d_in[6];
  const float* fw2 = (const float*)d_in[7];
  float* out = (float*)d_out;

  size_t shmem = sizeof(SMem);  // ~163 KB, fits gfx950's 160 KiB LDS
  hipFuncSetAttribute((const void*)dese_kernel,
                      hipFuncAttributeMaxDynamicSharedMemorySize, (int)shmem);
  hipLaunchKernelGGL(dese_kernel, dim3(256), dim3(1024), shmem, stream,
                     x, B0, C0, w1, w2, fw1, fw2, out);
}

// Round 2
// 677.895 us; speedup vs baseline: 3.5477x; 3.5477x over previous
//
#include <hip/hip_runtime.h>

// DeSELayer: per-sample CP-ALS(rank4, 20 it) -> rank_fc -> SE fc -> sigmoid gate.
// Gram-trick: iterations run on Gram = T0^T T0 (196x196, LDS-resident).
// 1 workgroup (1024 thr) per sample; grid = 256 = #CUs.
// R2: spill fix — launch_bounds(1024,4) (VGPR cap 128, LDS already limits to
// 1 block/CU) + phase-1 acc 64->49 floats (acc[3][4][4] + scalar row-48 strip).

#define EPSV 1e-6f

#define SM_G    0
#define SM_COF  16
#define SM_GINV 32
#define SM_M    48
#define SM_ATA  104

struct SMem {
  float gram[196 * 197];          // 154,448 B, stride 197 (odd -> conflict-free)
  union {
    float stage[8 * 200];         // phase-1 staging (8 rows x 200-padded)
    struct {
      float H[196 * 5];           // stride 5
      float Y[196 * 5];           // stride 5; epilogue: y[512] @0, z[32] @512
    } p2;
  } u;
  float B[56];                    // B[j][r] flat j*4+r
  float C[56];
  float Sm[120];                  // G,COF,GINV,M(56),ATA
};

__device__ __forceinline__ float rlane(float v, int l) {
  return __uint_as_float(__builtin_amdgcn_readlane(__float_as_uint(v), l));
}
__device__ __forceinline__ void fence_lds() { __threadfence_block(); }

// (V^T V)[r][s] for lanes (meaningful for l<16); V = 14x4 flat
__device__ __forceinline__ float gram16(const float* V, int l) {
  int r = (l >> 2) & 3, s = l & 3;
  float a = 0.f;
#pragma unroll
  for (int j = 0; j < 14; ++j) a += V[j * 4 + r] * V[j * 4 + s];
  return a;
}

// lanes 0..15 of wave 0: Sm[G..G+15] -> Sm[GINV..] via adjugate (G symmetric SPD + eps)
__device__ __forceinline__ void inv4x4(SMem* sm, int l) {
  if (l < 16) {
    float g[16];
#pragma unroll
    for (int t = 0; t < 16; ++t) g[t] = sm->Sm[SM_G + t];
    int r = l >> 2, s = l & 3;
    int r0 = (r == 0) ? 1 : 0, r1 = (r <= 1) ? 2 : 1, r2 = (r <= 2) ? 3 : 2;
    int c0 = (s == 0) ? 1 : 0, c1 = (s <= 1) ? 2 : 1, c2 = (s <= 2) ? 3 : 2;
    float a00 = g[r0 * 4 + c0], a01 = g[r0 * 4 + c1], a02 = g[r0 * 4 + c2];
    float a10 = g[r1 * 4 + c0], a11 = g[r1 * 4 + c1], a12 = g[r1 * 4 + c2];
    float a20 = g[r2 * 4 + c0], a21 = g[r2 * 4 + c1], a22 = g[r2 * 4 + c2];
    float d3 = a00 * (a11 * a22 - a12 * a21) - a01 * (a10 * a22 - a12 * a20)
             + a02 * (a10 * a21 - a11 * a20);
    sm->Sm[SM_COF + l] = ((r + s) & 1) ? -d3 : d3;
  }
  fence_lds();
  if (l < 16) {
    float det = sm->Sm[SM_G + 0] * sm->Sm[SM_COF + 0] + sm->Sm[SM_G + 1] * sm->Sm[SM_COF + 1]
              + sm->Sm[SM_G + 2] * sm->Sm[SM_COF + 2] + sm->Sm[SM_G + 3] * sm->Sm[SM_COF + 3];
    int r = l >> 2, s = l & 3;
    sm->Sm[SM_GINV + l] = sm->Sm[SM_COF + s * 4 + r] / det;  // adj = cof^T
  }
  fence_lds();
}

// wave 0: H[p][r] = sum_s B[j][s]C[k][s] * Ginv[s][r]; zero Y for next accumulation
__device__ __forceinline__ void computeH_zeroY(SMem* sm, int l) {
#pragma unroll
  for (int k4 = 0; k4 < 4; ++k4) {
    int p = l + 64 * k4;
    if (p < 196) {
      int j = p / 14, kk = p - j * 14;
      float kr[4];
#pragma unroll
      for (int s = 0; s < 4; ++s) kr[s] = sm->B[j * 4 + s] * sm->C[kk * 4 + s];
#pragma unroll
      for (int r = 0; r < 4; ++r) {
        float h = kr[0] * sm->Sm[SM_GINV + 0 + r] + kr[1] * sm->Sm[SM_GINV + 4 + r]
                + kr[2] * sm->Sm[SM_GINV + 8 + r] + kr[3] * sm->Sm[SM_GINV + 12 + r];
        sm->u.p2.H[p * 5 + r] = h;
      }
    }
  }
#pragma unroll
  for (int z = 0; z < 16; ++z) {
    int idx = l + 64 * z;
    if (idx < 980) sm->u.p2.Y[idx] = 0.f;
  }
}

__device__ __forceinline__ void initial_H(SMem* sm, int l) {
  float btb = gram16(sm->B, l);
  float ctc = gram16(sm->C, l);
  if (l < 16) {
    float dg = ((l >> 2) == (l & 3)) ? EPSV : 0.f;
    sm->Sm[SM_G + l] = btb * ctc + dg;
  }
  fence_lds();
  inv4x4(sm, l);
  computeH_zeroY(sm, l);
}

// wave 0: ATA in Sm[ATA], Y current. Updates B, C, then next H; zeroes Y.
__device__ __forceinline__ void factor_update(SMem* sm, int l) {
  int jj = l >> 2, r = l & 3;
  float dg = ((l >> 2) == (l & 3)) ? EPSV : 0.f;
  // --- B update: G_B = ATA o CtC(old) + eps ---
  float ctc_old = gram16(sm->C, l);
  if (l < 16) sm->Sm[SM_G + l] = sm->Sm[SM_ATA + l] * ctc_old + dg;
  fence_lds();
  inv4x4(sm, l);
  if (l < 56) {
    float m = 0.f;
#pragma unroll
    for (int k = 0; k < 14; ++k) m += sm->u.p2.Y[(jj * 14 + k) * 5 + r] * sm->C[k * 4 + r];
    sm->Sm[SM_M + l] = m;
  }
  fence_lds();
  if (l < 56) {
    float bn = 0.f;
#pragma unroll
    for (int s = 0; s < 4; ++s) bn += sm->Sm[SM_M + jj * 4 + s] * sm->Sm[SM_GINV + s * 4 + r];
    sm->B[l] = bn;
  }
  fence_lds();
  // --- C update: G_C = ATA o BtB(new) + eps ---
  float btb = gram16(sm->B, l);
  if (l < 16) sm->Sm[SM_G + l] = sm->Sm[SM_ATA + l] * btb + dg;
  fence_lds();
  inv4x4(sm, l);
  if (l < 56) {
    float m = 0.f;
#pragma unroll
    for (int j = 0; j < 14; ++j) m += sm->u.p2.Y[(j * 14 + jj) * 5 + r] * sm->B[j * 4 + r];
    sm->Sm[SM_M + l] = m;
  }
  fence_lds();
  if (l < 56) {
    float cn = 0.f;
#pragma unroll
    for (int s = 0; s < 4; ++s) cn += sm->Sm[SM_M + jj * 4 + s] * sm->Sm[SM_GINV + s * 4 + r];
    sm->C[l] = cn;
  }
  fence_lds();
  // --- next-iteration H: G_A = BtB(new) o CtC(new) + eps ---
  float ctc_new = gram16(sm->C, l);
  if (l < 16) sm->Sm[SM_G + l] = btb * ctc_new + dg;
  fence_lds();
  inv4x4(sm, l);
  computeH_zeroY(sm, l);
}

extern "C" __global__ void __launch_bounds__(1024, 4)
dese_kernel(const float* __restrict__ x, const float* __restrict__ B0,
            const float* __restrict__ C0, const float* __restrict__ w1,
            const float* __restrict__ w2, const float* __restrict__ fw1,
            const float* __restrict__ fw2, float* __restrict__ out) {
  extern __shared__ char smraw[];
  SMem* sm = (SMem*)smraw;
  const int tid = threadIdx.x;
  const int b = blockIdx.x;
  const int wv = tid >> 6;
  const int lane = tid & 63;
  const float* xb = x + (size_t)b * 100352;

  // load per-sample B0, C0 (A0 is dead: first ALS step overwrites A)
  if (tid < 56) sm->B[tid] = B0[b * 56 + tid];
  if (tid >= 64 && tid < 120) sm->C[tid - 64] = C0[b * 56 + (tid - 64)];

  // ================= Phase 1: Gram = T0^T T0 (196x196, K=512) =================
  // tile-rows 0..47 via acc[3][4][4] (tp = wv + 16*t3); rows 192..195 via one
  // scalar per active thread (784 entries). Keeps live VGPRs ~70 (no spill).
  {
    float acc[3][4][4];
#pragma unroll
    for (int a = 0; a < 3; ++a)
#pragma unroll
      for (int i = 0; i < 4; ++i)
#pragma unroll
        for (int j = 0; j < 4; ++j) acc[a][i][j] = 0.f;
    float acc2 = 0.f;
    const int e = wv * 49 + lane;          // 0..783 for lane<49
    const int r48 = 192 + e / 196;         // spatial row 192..195
    const int c48 = e - (e / 196) * 196;   // spatial col 0..195

    const float4* xs4 = (const float4*)xb;
    for (int ch = 0; ch < 64; ++ch) {
      __syncthreads();
      if (tid < 392) {  // stage 8 rows x 196 floats, coalesced float4
        float4 v = xs4[ch * 392 + tid];
        int row = tid / 49, col = tid - row * 49;
        *(float4*)&sm->u.stage[row * 200 + col * 4] = v;
      }
      __syncthreads();
      if (lane < 49) {
#pragma unroll
        for (int ii = 0; ii < 8; ++ii) {
          float4 bv = *(const float4*)&sm->u.stage[ii * 200 + lane * 4];
          float bb[4] = {bv.x, bv.y, bv.z, bv.w};
          acc2 += sm->u.stage[ii * 200 + r48] * sm->u.stage[ii * 200 + c48];
#pragma unroll
          for (int t3 = 0; t3 < 3; ++t3) {
            int tp = wv + 16 * t3;       // wave-uniform, 0..47
            float4 av = *(const float4*)&sm->u.stage[ii * 200 + tp * 4];
            float aa[4] = {av.x, av.y, av.z, av.w};
#pragma unroll
            for (int ai = 0; ai < 4; ++ai)
#pragma unroll
              for (int bi = 0; bi < 4; ++bi) acc[t3][ai][bi] += aa[ai] * bb[bi];
          }
        }
      }
    }
    __syncthreads();
    if (lane < 49) {
#pragma unroll
      for (int t3 = 0; t3 < 3; ++t3) {
        int tp = wv + 16 * t3;
#pragma unroll
        for (int ai = 0; ai < 4; ++ai)
#pragma unroll
          for (int bi = 0; bi < 4; ++bi)
            sm->gram[(tp * 4 + ai) * 197 + lane * 4 + bi] = acc[t3][ai][bi];
      }
      sm->gram[r48 * 197 + c48] = acc2;
    }
  }
  __syncthreads();

  // ================= Phase 2: 19 ALS iteration bodies on Gram =================
  // pre: H_1 from (B0,C0); iter i: Y=Gram*H, ATA=H^T Y, B,C updates, next H.
  // After iter 18 H == H_20; step-20 B/C are dead in the reference.
  if (tid < 64) initial_H(sm, lane);
  __syncthreads();

  for (int it = 0; it < 19; ++it) {
    // ---- Y[p][r] = sum_q Gram[p][q] H[q][r], 4-way q-split + LDS atomics ----
    {
      int qg = tid >> 8;        // 0..3  (wave-uniform: 256-aligned groups)
      int pp = tid & 255;       // p (active < 196)
      float hreg[4];            // window H[qg*49 .. qg*49+48][0..3] dense across lanes
#pragma unroll
      for (int k = 0; k < 4; ++k) {
        int wi = 64 * k + lane;
        int q = qg * 49 + (wi >> 2);
        hreg[k] = (wi < 196) ? sm->u.p2.H[q * 5 + (wi & 3)] : 0.f;
      }
      if (pp < 196) {
        const float* grow = sm->gram + pp * 197 + qg * 49;
        float a0 = 0.f, a1 = 0.f, a2 = 0.f, a3 = 0.f;
#pragma unroll
        for (int qq = 0; qq < 49; ++qq) {
          float g = grow[qq];
          a0 += g * rlane(hreg[(4 * qq + 0) >> 6], (4 * qq + 0) & 63);
          a1 += g * rlane(hreg[(4 * qq + 1) >> 6], (4 * qq + 1) & 63);
          a2 += g * rlane(hreg[(4 * qq + 2) >> 6], (4 * qq + 2) & 63);
          a3 += g * rlane(hreg[(4 * qq + 3) >> 6], (4 * qq + 3) & 63);
        }
        atomicAdd(&sm->u.p2.Y[pp * 5 + 0], a0);
        atomicAdd(&sm->u.p2.Y[pp * 5 + 1], a1);
        atomicAdd(&sm->u.p2.Y[pp * 5 + 2], a2);
        atomicAdd(&sm->u.p2.Y[pp * 5 + 3], a3);
      }
    }
    __syncthreads();
    // ---- ATA[r][s] = sum_p H[p][r] Y[p][s]; wave w handles (r,s)=w ----
    {
      int r = wv >> 2, s = wv & 3;
      float a = 0.f;
#pragma unroll
      for (int k4 = 0; k4 < 4; ++k4) {
        int p = lane + 64 * k4;
        if (p < 196) a += sm->u.p2.H[p * 5 + r] * sm->u.p2.Y[p * 5 + s];
      }
#pragma unroll
      for (int m = 32; m > 0; m >>= 1) a += __shfl_xor(a, m, 64);
      if (lane == 0) sm->Sm[SM_ATA + wv] = a;
    }
    __syncthreads();
    if (tid < 64) factor_update(sm, lane);
    __syncthreads();
  }

  // ================= Epilogue =================
  // y[i] = w2 . relu(w1 . (T0[i,:] H))   for i in 0..511
  {
    float hr[13];  // dense H (4p+r) spread over lanes, all waves load
#pragma unroll
    for (int k = 0; k < 13; ++k) {
      int d = 64 * k + lane;
      hr[k] = (d < 784) ? sm->u.p2.H[(d >> 2) * 5 + (d & 3)] : 0.f;
    }
    if (tid < 512) {
      const float4* row = (const float4*)(xb + tid * 196);
      float a0 = 0.f, a1 = 0.f, a2 = 0.f, a3 = 0.f;
#pragma unroll
      for (int f4 = 0; f4 < 49; ++f4) {
        float4 v = row[f4];
        float vv[4] = {v.x, v.y, v.z, v.w};
#pragma unroll
        for (int j = 0; j < 4; ++j) {
          int d = 16 * f4 + 4 * j;
          a0 += vv[j] * rlane(hr[(d + 0) >> 6], (d + 0) & 63);
          a1 += vv[j] * rlane(hr[(d + 1) >> 6], (d + 1) & 63);
          a2 += vv[j] * rlane(hr[(d + 2) >> 6], (d + 2) & 63);
          a3 += vv[j] * rlane(hr[(d + 3) >> 6], (d + 3) & 63);
        }
      }
      float y = 0.f;
#pragma unroll
      for (int s = 0; s < 4; ++s) {
        float pre = w1[s * 4 + 0] * a0 + w1[s * 4 + 1] * a1 + w1[s * 4 + 2] * a2
                  + w1[s * 4 + 3] * a3;
        y += w2[s] * fmaxf(pre, 0.f);
      }
      sm->u.p2.Y[tid] = y;
    }
  }
  __syncthreads();
  // z[u] = relu(sum_c y[c] fw1[u][c]) : 32 lanes per u, half-wave reduce
  {
    int u = tid >> 5, lc = tid & 31;
    float a = 0.f;
#pragma unroll
    for (int k = 0; k < 16; ++k) {
      int c = lc + 32 * k;
      a += sm->u.p2.Y[c] * fw1[u * 512 + c];
    }
    a += __shfl_xor(a, 1, 64);
    a += __shfl_xor(a, 2, 64);
    a += __shfl_xor(a, 4, 64);
    a += __shfl_xor(a, 8, 64);
    a += __shfl_xor(a, 16, 64);
    if (lc == 0) sm->u.p2.Y[512 + u] = fmaxf(a, 0.f);
  }
  __syncthreads();
  // gate[c] = sigmoid(sum_u z[u] fw2[c][u])
  if (tid < 512) {
    const float4* f2r = (const float4*)(fw2 + tid * 32);
    float za = 0.f;
#pragma unroll
    for (int u4 = 0; u4 < 8; ++u4) {
      float4 fv = f2r[u4];
      za += fv.x * sm->u.p2.Y[512 + u4 * 4 + 0];
      za += fv.y * sm->u.p2.Y[512 + u4 * 4 + 1];
      za += fv.z * sm->u.p2.Y[512 + u4 * 4 + 2];
      za += fv.w * sm->u.p2.Y[512 + u4 * 4 + 3];
    }
    float g = 1.f / (1.f + __expf(-za));
    sm->u.p2.Y[tid] = g;  // y dead -> reuse as gate
  }
  __syncthreads();
  // out = x * gate  (float4, coalesced; 49 float4 per channel)
  {
    const float4* xi = (const float4*)xb;
    float4* oo = (float4*)(out + (size_t)b * 100352);
#pragma unroll
    for (int t = 0; t < 25; ++t) {
      int v = tid + t * 1024;
      if (v < 25088) {
        float4 q = xi[v];
        float g = sm->u.p2.Y[v / 49];
        oo[v] = make_float4(q.x * g, q.y * g, q.z * g, q.w * g);
      }
    }
  }
}

extern "C" void kernel_launch(void* const* d_in, const int* in_sizes, int n_in,
                              void* d_out, int out_size, void* d_ws, size_t ws_size,
                              hipStream_t stream) {
  (void)in_sizes; (void)n_in; (void)d_ws; (void)ws_size; (void)out_size;
  const float* x   = (const float*)d_in[0];
  // d_in[1] = A0: unused (overwritten before first use in the reference)
  const float* B0  = (const float*)d_in[2];
  const float* C0  = (const float*)d_in[3];
  const float* w1  = (const float*)d_in[4];
  const float* w2  = (const float*)d_in[5];
  const float* fw1 = (const float*)d_in[6];
  const float* fw2 = (const float*)d_in[7];
  float* out = (float*)d_out;

  size_t shmem = sizeof(SMem);  // ~163 KB, fits gfx950's 160 KiB LDS
  hipFuncSetAttribute((const void*)dese_kernel,
                      hipFuncAttributeMaxDynamicSharedMemorySize, (int)shmem);
  hipLaunchKernelGGL(dese_kernel, dim3(256), dim3(1024), shmem, stream,
                     x, B0, C0, w1, w2, fw1, fw2, out);
}

// Round 3
// 470.711 us; speedup vs baseline: 5.1093x; 1.4402x over previous
//
#include <hip/hip_runtime.h>

// DeSELayer: per-sample CP-ALS(rank4, 20 it) -> rank_fc -> SE fc -> sigmoid gate.
// Gram-trick: iterations run on Gram = T0^T T0 (196x196, LDS-resident).
// 1 workgroup (1024 thr) per sample; grid = 256 = #CUs.
// R2: spill fix (launch_bounds(1024,4)).
// R3: phase-1 Gram via MFMA split-bf16: Gram = hi*hi^T + hi*lo^T + lo*hi^T,
//     fragments pre-packed in LDS (contiguous b128 reads), fp32 accum in VGPRs.

#define EPSV 1e-6f

#define SM_G    0
#define SM_COF  16
#define SM_GINV 32
#define SM_M    48
#define SM_ATA  104

typedef __attribute__((ext_vector_type(8))) short short8;
typedef __attribute__((ext_vector_type(4))) float float4v;

struct SMem {
  union {
    struct {                      // ---- phase 1 ----
      short xhi[4 * 13 * 64 * 8]; // frag-order: [kstep s][tile T][lane][8 ch] bf16
      short xlo[4 * 13 * 64 * 8]; // 53,248 B each
      float stage_f[64 * 200];    // 51,200 B transpose staging (64 ch x 196 p)
    } p1;
    struct {                      // ---- phase 2 ----
      float gram[196 * 197];      // 154,448 B, stride 197 (odd -> conflict-free)
      float H[196 * 5];           // stride 5
      float Y[196 * 5];           // stride 5; epilogue: y[512] @0, z[32] @512
    } p2;
  } u;
  float B[56];                    // B[j][r] flat j*4+r
  float C[56];
  float Sm[120];                  // G,COF,GINV,M(56),ATA
};

__device__ __forceinline__ float rlane(float v, int l) {
  return __uint_as_float(__builtin_amdgcn_readlane(__float_as_uint(v), l));
}
__device__ __forceinline__ void fence_lds() { __threadfence_block(); }

// round-to-nearest-even fp32 -> bf16 (returned in low 16 bits)
__device__ __forceinline__ unsigned bf16rne(float f) {
  unsigned u = __float_as_uint(f);
  return (u + 0x7FFFu + ((u >> 16) & 1u)) >> 16;
}

// (V^T V)[r][s] for lanes (meaningful for l<16); V = 14x4 flat
__device__ __forceinline__ float gram16(const float* V, int l) {
  int r = (l >> 2) & 3, s = l & 3;
  float a = 0.f;
#pragma unroll
  for (int j = 0; j < 14; ++j) a += V[j * 4 + r] * V[j * 4 + s];
  return a;
}

// lanes 0..15 of wave 0: Sm[G..G+15] -> Sm[GINV..] via adjugate (G symmetric SPD + eps)
__device__ __forceinline__ void inv4x4(SMem* sm, int l) {
  if (l < 16) {
    float g[16];
#pragma unroll
    for (int t = 0; t < 16; ++t) g[t] = sm->Sm[SM_G + t];
    int r = l >> 2, s = l & 3;
    int r0 = (r == 0) ? 1 : 0, r1 = (r <= 1) ? 2 : 1, r2 = (r <= 2) ? 3 : 2;
    int c0 = (s == 0) ? 1 : 0, c1 = (s <= 1) ? 2 : 1, c2 = (s <= 2) ? 3 : 2;
    float a00 = g[r0 * 4 + c0], a01 = g[r0 * 4 + c1], a02 = g[r0 * 4 + c2];
    float a10 = g[r1 * 4 + c0], a11 = g[r1 * 4 + c1], a12 = g[r1 * 4 + c2];
    float a20 = g[r2 * 4 + c0], a21 = g[r2 * 4 + c1], a22 = g[r2 * 4 + c2];
    float d3 = a00 * (a11 * a22 - a12 * a21) - a01 * (a10 * a22 - a12 * a20)
             + a02 * (a10 * a21 - a11 * a20);
    sm->Sm[SM_COF + l] = ((r + s) & 1) ? -d3 : d3;
  }
  fence_lds();
  if (l < 16) {
    float det = sm->Sm[SM_G + 0] * sm->Sm[SM_COF + 0] + sm->Sm[SM_G + 1] * sm->Sm[SM_COF + 1]
              + sm->Sm[SM_G + 2] * sm->Sm[SM_COF + 2] + sm->Sm[SM_G + 3] * sm->Sm[SM_COF + 3];
    int r = l >> 2, s = l & 3;
    sm->Sm[SM_GINV + l] = sm->Sm[SM_COF + s * 4 + r] / det;  // adj = cof^T
  }
  fence_lds();
}

// wave 0: H[p][r] = sum_s B[j][s]C[k][s] * Ginv[s][r]; zero Y for next accumulation
__device__ __forceinline__ void computeH_zeroY(SMem* sm, int l) {
#pragma unroll
  for (int k4 = 0; k4 < 4; ++k4) {
    int p = l + 64 * k4;
    if (p < 196) {
      int j = p / 14, kk = p - j * 14;
      float kr[4];
#pragma unroll
      for (int s = 0; s < 4; ++s) kr[s] = sm->B[j * 4 + s] * sm->C[kk * 4 + s];
#pragma unroll
      for (int r = 0; r < 4; ++r) {
        float h = kr[0] * sm->Sm[SM_GINV + 0 + r] + kr[1] * sm->Sm[SM_GINV + 4 + r]
                + kr[2] * sm->Sm[SM_GINV + 8 + r] + kr[3] * sm->Sm[SM_GINV + 12 + r];
        sm->u.p2.H[p * 5 + r] = h;
      }
    }
  }
#pragma unroll
  for (int z = 0; z < 16; ++z) {
    int idx = l + 64 * z;
    if (idx < 980) sm->u.p2.Y[idx] = 0.f;
  }
}

__device__ __forceinline__ void initial_H(SMem* sm, int l) {
  float btb = gram16(sm->B, l);
  float ctc = gram16(sm->C, l);
  if (l < 16) {
    float dg = ((l >> 2) == (l & 3)) ? EPSV : 0.f;
    sm->Sm[SM_G + l] = btb * ctc + dg;
  }
  fence_lds();
  inv4x4(sm, l);
  computeH_zeroY(sm, l);
}

// wave 0: ATA in Sm[ATA], Y current. Updates B, C, then next H; zeroes Y.
__device__ __forceinline__ void factor_update(SMem* sm, int l) {
  int jj = l >> 2, r = l & 3;
  float dg = ((l >> 2) == (l & 3)) ? EPSV : 0.f;
  // --- B update: G_B = ATA o CtC(old) + eps ---
  float ctc_old = gram16(sm->C, l);
  if (l < 16) sm->Sm[SM_G + l] = sm->Sm[SM_ATA + l] * ctc_old + dg;
  fence_lds();
  inv4x4(sm, l);
  if (l < 56) {
    float m = 0.f;
#pragma unroll
    for (int k = 0; k < 14; ++k) m += sm->u.p2.Y[(jj * 14 + k) * 5 + r] * sm->C[k * 4 + r];
    sm->Sm[SM_M + l] = m;
  }
  fence_lds();
  if (l < 56) {
    float bn = 0.f;
#pragma unroll
    for (int s = 0; s < 4; ++s) bn += sm->Sm[SM_M + jj * 4 + s] * sm->Sm[SM_GINV + s * 4 + r];
    sm->B[l] = bn;
  }
  fence_lds();
  // --- C update: G_C = ATA o BtB(new) + eps ---
  float btb = gram16(sm->B, l);
  if (l < 16) sm->Sm[SM_G + l] = sm->Sm[SM_ATA + l] * btb + dg;
  fence_lds();
  inv4x4(sm, l);
  if (l < 56) {
    float m = 0.f;
#pragma unroll
    for (int j = 0; j < 14; ++j) m += sm->u.p2.Y[(j * 14 + jj) * 5 + r] * sm->B[j * 4 + r];
    sm->Sm[SM_M + l] = m;
  }
  fence_lds();
  if (l < 56) {
    float cn = 0.f;
#pragma unroll
    for (int s = 0; s < 4; ++s) cn += sm->Sm[SM_M + jj * 4 + s] * sm->Sm[SM_GINV + s * 4 + r];
    sm->C[l] = cn;
  }
  fence_lds();
  // --- next-iteration H: G_A = BtB(new) o CtC(new) + eps ---
  float ctc_new = gram16(sm->C, l);
  if (l < 16) sm->Sm[SM_G + l] = btb * ctc_new + dg;
  fence_lds();
  inv4x4(sm, l);
  computeH_zeroY(sm, l);
}

extern "C" __global__ void __launch_bounds__(1024, 4)
dese_kernel(const float* __restrict__ x, const float* __restrict__ B0,
            const float* __restrict__ C0, const float* __restrict__ w1,
            const float* __restrict__ w2, const float* __restrict__ fw1,
            const float* __restrict__ fw2, float* __restrict__ out) {
  extern __shared__ char smraw[];
  SMem* sm = (SMem*)smraw;
  const int tid = threadIdx.x;
  const int b = blockIdx.x;
  const int wv = tid >> 6;
  const int lane = tid & 63;
  const float* xb = x + (size_t)b * 100352;

  // load per-sample B0, C0 (A0 is dead: first ALS step overwrites A)
  if (tid < 56) sm->B[tid] = B0[b * 56 + tid];
  if (tid >= 64 && tid < 120) sm->C[tid - 64] = C0[b * 56 + (tid - 64)];

  // ================= Phase 1: Gram = X X^T via MFMA split-bf16 =================
  // X = T0^T (196 spatial x 512 ch), padded to 208 rows (13 tiles of 16).
  // Gram tile (I,J), I<=J: acc += hi_I*hi_J + hi_I*lo_J + lo_I*hi_J (fp32 acc).
  // 96 tile-slots over 16 waves (6 each, 91 valid). K chunked 4x128 ch.
  {
    float4v acc[6];
#pragma unroll
    for (int i = 0; i < 6; ++i) acc[i] = (float4v){0.f, 0.f, 0.f, 0.f};

    int TI[6], TJ[6], TVv[6];
#pragma unroll
    for (int i = 0; i < 6; ++i) {
      int t = wv * 6 + i;
      int valid = (t < 91);
      int I = 0, cum = 0;
      if (valid) {
        while (t >= cum + (13 - I)) { cum += (13 - I); ++I; }
      }
      TI[i] = valid ? I : 0;
      TJ[i] = valid ? (I + t - cum) : 0;
      TVv[i] = valid;
    }

    const float4* x4 = (const float4*)xb;
    for (int chunk = 0; chunk < 4; ++chunk) {
#pragma unroll
      for (int slab = 0; slab < 2; ++slab) {
        const int cb = chunk * 128 + slab * 64;   // base channel of 64-ch slab
        __syncthreads();  // prev MFMA/transpose readers done
        // ---- global -> stage_f: 64 ch x 196 p fp32, coalesced float4 ----
#pragma unroll
        for (int j = 0; j < 4; ++j) {
          int fi = tid + 1024 * j;
          if (fi < 3136) {
            int ch = fi / 49, i4 = fi - ch * 49;
            float4 v = x4[(size_t)(cb + ch) * 49 + i4];
            *(float4*)&sm->u.p1.stage_f[ch * 200 + i4 * 4] = v;
          }
        }
        __syncthreads();
        // ---- transpose + hi/lo split -> fragment-order bf16 ----
        int p = tid & 255, chgrp = tid >> 8;      // p: spatial row; chgrp: 16-ch group
        if (p < 208) {
#pragma unroll
          for (int oct = 0; oct < 2; ++oct) {
            unsigned hp[4], lp[4];
#pragma unroll
            for (int ii = 0; ii < 8; ++ii) {
              int ch = chgrp * 16 + oct * 8 + ii;
              float v = (p < 196) ? sm->u.p1.stage_f[ch * 200 + p] : 0.f;
              unsigned h = bf16rne(v);
              float hf = __uint_as_float(h << 16);
              unsigned l = bf16rne(v - hf);
              if (ii & 1) { hp[ii >> 1] |= (h << 16); lp[ii >> 1] |= (l << 16); }
              else        { hp[ii >> 1] = h;          lp[ii >> 1] = l; }
            }
            int o = slab * 8 + chgrp * 2 + oct;   // ch-octet index within 128-chunk
            int fidx = ((o >> 2) * 13 + (p >> 4)) * 64 + (((o & 3) << 4) | (p & 15));
            *(uint4*)&sm->u.p1.xhi[fidx * 8] = make_uint4(hp[0], hp[1], hp[2], hp[3]);
            *(uint4*)&sm->u.p1.xlo[fidx * 8] = make_uint4(lp[0], lp[1], lp[2], lp[3]);
          }
        }
      }
      __syncthreads();  // XTfrag chunk complete
      // ---- MFMA: 4 ksteps (K=32 each) x 6 tiles; contiguous-1KB b128 frag reads ----
#pragma unroll
      for (int s = 0; s < 4; ++s) {
#pragma unroll
        for (int ti = 0; ti < 6; ++ti) {
          const short8 aH = *(const short8*)&sm->u.p1.xhi[((s * 13 + TI[ti]) * 64 + lane) * 8];
          const short8 aL = *(const short8*)&sm->u.p1.xlo[((s * 13 + TI[ti]) * 64 + lane) * 8];
          const short8 bH = *(const short8*)&sm->u.p1.xhi[((s * 13 + TJ[ti]) * 64 + lane) * 8];
          const short8 bL = *(const short8*)&sm->u.p1.xlo[((s * 13 + TJ[ti]) * 64 + lane) * 8];
          acc[ti] = __builtin_amdgcn_mfma_f32_16x16x32_bf16(aH, bH, acc[ti], 0, 0, 0);
          acc[ti] = __builtin_amdgcn_mfma_f32_16x16x32_bf16(aH, bL, acc[ti], 0, 0, 0);
          acc[ti] = __builtin_amdgcn_mfma_f32_16x16x32_bf16(aL, bH, acc[ti], 0, 0, 0);
        }
      }
    }
    __syncthreads();  // all MFMA frag reads done; p1 region now dead
    // ---- write acc -> gram (C/D layout: col=lane&15, row=quad*4+reg) + mirror ----
    {
      int col = lane & 15, quad = lane >> 4;
#pragma unroll
      for (int ti = 0; ti < 6; ++ti) {
        if (TVv[ti]) {
#pragma unroll
          for (int reg = 0; reg < 4; ++reg) {
            int pr = TI[ti] * 16 + quad * 4 + reg;
            int pc = TJ[ti] * 16 + col;
            if (pr < 196 && pc < 196) {
              float v = acc[ti][reg];
              sm->u.p2.gram[pr * 197 + pc] = v;
              sm->u.p2.gram[pc * 197 + pr] = v;
            }
          }
        }
      }
    }
  }
  __syncthreads();

  // ================= Phase 2: 19 ALS iteration bodies on Gram =================
  // pre: H_1 from (B0,C0); iter i: Y=Gram*H, ATA=H^T Y, B,C updates, next H.
  // After iter 18 H == H_20; step-20 B/C are dead in the reference.
  if (tid < 64) initial_H(sm, lane);
  __syncthreads();

  for (int it = 0; it < 19; ++it) {
    // ---- Y[p][r] = sum_q Gram[p][q] H[q][r], 4-way q-split + LDS atomics ----
    {
      int qg = tid >> 8;        // 0..3  (wave-uniform: 256-aligned groups)
      int pp = tid & 255;       // p (active < 196)
      float hreg[4];            // window H[qg*49 .. qg*49+48][0..3] dense across lanes
#pragma unroll
      for (int k = 0; k < 4; ++k) {
        int wi = 64 * k + lane;
        int q = qg * 49 + (wi >> 2);
        hreg[k] = (wi < 196) ? sm->u.p2.H[q * 5 + (wi & 3)] : 0.f;
      }
      if (pp < 196) {
        const float* grow = sm->u.p2.gram + pp * 197 + qg * 49;
        float a0 = 0.f, a1 = 0.f, a2 = 0.f, a3 = 0.f;
#pragma unroll
        for (int qq = 0; qq < 49; ++qq) {
          float g = grow[qq];
          a0 += g * rlane(hreg[(4 * qq + 0) >> 6], (4 * qq + 0) & 63);
          a1 += g * rlane(hreg[(4 * qq + 1) >> 6], (4 * qq + 1) & 63);
          a2 += g * rlane(hreg[(4 * qq + 2) >> 6], (4 * qq + 2) & 63);
          a3 += g * rlane(hreg[(4 * qq + 3) >> 6], (4 * qq + 3) & 63);
        }
        atomicAdd(&sm->u.p2.Y[pp * 5 + 0], a0);
        atomicAdd(&sm->u.p2.Y[pp * 5 + 1], a1);
        atomicAdd(&sm->u.p2.Y[pp * 5 + 2], a2);
        atomicAdd(&sm->u.p2.Y[pp * 5 + 3], a3);
      }
    }
    __syncthreads();
    // ---- ATA[r][s] = sum_p H[p][r] Y[p][s]; wave w handles (r,s)=w ----
    {
      int r = wv >> 2, s = wv & 3;
      float a = 0.f;
#pragma unroll
      for (int k4 = 0; k4 < 4; ++k4) {
        int p = lane + 64 * k4;
        if (p < 196) a += sm->u.p2.H[p * 5 + r] * sm->u.p2.Y[p * 5 + s];
      }
#pragma unroll
      for (int m = 32; m > 0; m >>= 1) a += __shfl_xor(a, m, 64);
      if (lane == 0) sm->Sm[SM_ATA + wv] = a;
    }
    __syncthreads();
    if (tid < 64) factor_update(sm, lane);
    __syncthreads();
  }

  // ================= Epilogue =================
  // y[i] = w2 . relu(w1 . (T0[i,:] H))   for i in 0..511
  {
    float hr[13];  // dense H (4p+r) spread over lanes, all waves load
#pragma unroll
    for (int k = 0; k < 13; ++k) {
      int d = 64 * k + lane;
      hr[k] = (d < 784) ? sm->u.p2.H[(d >> 2) * 5 + (d & 3)] : 0.f;
    }
    if (tid < 512) {
      const float4* row = (const float4*)(xb + tid * 196);
      float a0 = 0.f, a1 = 0.f, a2 = 0.f, a3 = 0.f;
#pragma unroll
      for (int f4 = 0; f4 < 49; ++f4) {
        float4 v = row[f4];
        float vv[4] = {v.x, v.y, v.z, v.w};
#pragma unroll
        for (int j = 0; j < 4; ++j) {
          int d = 16 * f4 + 4 * j;
          a0 += vv[j] * rlane(hr[(d + 0) >> 6], (d + 0) & 63);
          a1 += vv[j] * rlane(hr[(d + 1) >> 6], (d + 1) & 63);
          a2 += vv[j] * rlane(hr[(d + 2) >> 6], (d + 2) & 63);
          a3 += vv[j] * rlane(hr[(d + 3) >> 6], (d + 3) & 63);
        }
      }
      float y = 0.f;
#pragma unroll
      for (int s = 0; s < 4; ++s) {
        float pre = w1[s * 4 + 0] * a0 + w1[s * 4 + 1] * a1 + w1[s * 4 + 2] * a2
                  + w1[s * 4 + 3] * a3;
        y += w2[s] * fmaxf(pre, 0.f);
      }
      sm->u.p2.Y[tid] = y;
    }
  }
  __syncthreads();
  // z[u] = relu(sum_c y[c] fw1[u][c]) : 32 lanes per u, half-wave reduce
  {
    int u = tid >> 5, lc = tid & 31;
    float a = 0.f;
#pragma unroll
    for (int k = 0; k < 16; ++k) {
      int c = lc + 32 * k;
      a += sm->u.p2.Y[c] * fw1[u * 512 + c];
    }
    a += __shfl_xor(a, 1, 64);
    a += __shfl_xor(a, 2, 64);
    a += __shfl_xor(a, 4, 64);
    a += __shfl_xor(a, 8, 64);
    a += __shfl_xor(a, 16, 64);
    if (lc == 0) sm->u.p2.Y[512 + u] = fmaxf(a, 0.f);
  }
  __syncthreads();
  // gate[c] = sigmoid(sum_u z[u] fw2[c][u])
  if (tid < 512) {
    const float4* f2r = (const float4*)(fw2 + tid * 32);
    float za = 0.f;
#pragma unroll
    for (int u4 = 0; u4 < 8; ++u4) {
      float4 fv = f2r[u4];
      za += fv.x * sm->u.p2.Y[512 + u4 * 4 + 0];
      za += fv.y * sm->u.p2.Y[512 + u4 * 4 + 1];
      za += fv.z * sm->u.p2.Y[512 + u4 * 4 + 2];
      za += fv.w * sm->u.p2.Y[512 + u4 * 4 + 3];
    }
    float g = 1.f / (1.f + __expf(-za));
    sm->u.p2.Y[tid] = g;  // y dead -> reuse as gate
  }
  __syncthreads();
  // out = x * gate  (float4, coalesced; 49 float4 per channel)
  {
    const float4* xi = (const float4*)xb;
    float4* oo = (float4*)(out + (size_t)b * 100352);
#pragma unroll
    for (int t = 0; t < 25; ++t) {
      int v = tid + t * 1024;
      if (v < 25088) {
        float4 q = xi[v];
        float g = sm->u.p2.Y[v / 49];
        oo[v] = make_float4(q.x * g, q.y * g, q.z * g, q.w * g);
      }
    }
  }
}

extern "C" void kernel_launch(void* const* d_in, const int* in_sizes, int n_in,
                              void* d_out, int out_size, void* d_ws, size_t ws_size,
                              hipStream_t stream) {
  (void)in_sizes; (void)n_in; (void)d_ws; (void)ws_size; (void)out_size;
  const float* x   = (const float*)d_in[0];
  // d_in[1] = A0: unused (overwritten before first use in the reference)
  const float* B0  = (const float*)d_in[2];
  const float* C0  = (const float*)d_in[3];
  const float* w1  = (const float*)d_in[4];
  const float* w2  = (const float*)d_in[5];
  const float* fw1 = (const float*)d_in[6];
  const float* fw2 = (const float*)d_in[7];
  float* out = (float*)d_out;

  size_t shmem = sizeof(SMem);  // ~163 KB, fits gfx950's 160 KiB LDS
  hipFuncSetAttribute((const void*)dese_kernel,
                      hipFuncAttributeMaxDynamicSharedMemorySize, (int)shmem);
  hipLaunchKernelGGL(dese_kernel, dim3(256), dim3(1024), shmem, stream,
                     x, B0, C0, w1, w2, fw1, fw2, out);
}